// Round 8
// baseline (949.944 us; speedup 1.0000x reference)
//
#include <hip/hip_runtime.h>
#include <math.h>

typedef _Float16 h2 __attribute__((ext_vector_type(2)));
typedef unsigned int u32;

#define T_STEPS 1024
#define B_SZ    256
#define K_DIM   128
#define IN_DIM  64
#define M_DIM   63
#define NTH     512

__device__ __forceinline__ h2 as_h2(u32 v) { union { u32 u; h2 h; } c; c.u = v; return c.h; }

#if __has_builtin(__builtin_amdgcn_fdot2)
__device__ __forceinline__ float dot2(h2 a, h2 b, float acc) {
    return __builtin_amdgcn_fdot2(a, b, acc, false);
}
#else
__device__ __forceinline__ float dot2(h2 a, h2 b, float acc) {
    return acc + (float)a.x * (float)b.x + (float)a.y * (float)b.y;
}
#endif

// LDS-only barrier: do NOT drain vmcnt (x prefetch / y stores stay in flight).
__device__ __forceinline__ void block_sync_lds() {
    asm volatile("s_waitcnt lgkmcnt(0)\n\ts_barrier" ::: "memory");
}

__global__ __launch_bounds__(NTH)
void lstm_fused(const float* __restrict__ x,   // [B,T,IN]
                const float* __restrict__ Wi, const float* __restrict__ Ui,
                const float* __restrict__ Wf, const float* __restrict__ Uf,
                const float* __restrict__ Wg, const float* __restrict__ Ug,
                const float* __restrict__ Wo, const float* __restrict__ Uo,
                const float* __restrict__ Vw, const float* __restrict__ Vb,
                float* __restrict__ out)       // [B,T,M]
{
    // hx: packed-f16 activations, double-buffered. h2[0..63] = h, h2[64..95] = x_t
    __shared__ __align__(16) h2 hx[2][96];

    const int b   = blockIdx.x;
    const int tid = threadIdx.x;
    const int rg  = tid >> 3;       // 8-lane group id (0..63)
    const int cb  = tid & 7;        // col-block within group
    const int lane_g = tid & 3;     // gate owned after reduce
    const int kown   = tid >> 2;    // hidden unit owned (lanes with lane_g==0)

    // ---- weights: thread (rg,cb) holds 8 rows {gate 0..3}x{unit 2rg,2rg+1},
    //      h2-cols cb*12 .. cb*12+11 of the 96-h2 concat [Uh(64) | Wx(32)]
    h2 w[8][12];   // 96 VGPRs
    #pragma unroll
    for (int c = 0; c < 8; ++c) {
        const int gate = c & 3;                 // compile-time after unroll
        const int k    = 2 * rg + (c >> 2);
        const float* U = (gate == 0) ? Ui : (gate == 1) ? Uf : (gate == 2) ? Ug : Uo;
        const float* W = (gate == 0) ? Wi : (gate == 1) ? Wf : (gate == 2) ? Wg : Wo;
        const float* urow = U + k * K_DIM;
        const float* wrow = W + k * IN_DIM;
        #pragma unroll
        for (int i = 0; i < 12; ++i) {
            int j = cb * 12 + i;                // h2 col in concat layout
            const float* s = (j < 64) ? (urow + 2 * j) : (wrow + 2 * (j - 64));
            float2 v = *(const float2*)s;
            w[c][i] = h2{(_Float16)v.x, (_Float16)v.y};
        }
    }

    // ---- y-projection: 8 threads per output row; Vw chunk in registers ----
    const int  ym   = rg;                       // 0..63 (63 used)
    const bool is_y = (tid < 504);
    h2 vwreg[8] = {};
    float vbv = 0.0f;
    if (is_y) {
        const float* src = Vw + ym * K_DIM + cb * 16;
        #pragma unroll
        for (int i = 0; i < 8; ++i)
            vwreg[i] = h2{(_Float16)src[2 * i], (_Float16)src[2 * i + 1]};
        if (cb == 0) vbv = Vb[ym];
    }

    const size_t xbase = (size_t)b * T_STEPS * IN_DIM;
    const size_t obase = (size_t)b * T_STEPS * M_DIM;

    // ---- init: h_{-1}=0, x_0 staged ----
    if (tid < 64) {
        hx[0][tid] = h2{(_Float16)0.f, (_Float16)0.f};
        ((_Float16*)hx[0])[128 + tid] = (_Float16)x[xbase + tid];
    }
    float c = 0.0f;   // c[kown], meaningful on lane_g==0
    __syncthreads();

    for (int t = 0; t < T_STEPS; ++t) {
        const int par = t & 1;

        // x_{t+1} prefetch (wave 0; stays in flight across the LDS barrier)
        float xv = 0.0f;
        if (t + 1 < T_STEPS && tid < 64)
            xv = x[xbase + (size_t)(t + 1) * IN_DIM + tid];

        // tanh(c_prev) — depends only on last step, hidden under the dots
        float tc;
        {
            float e = __expf(-2.0f * c);
            tc = 2.0f * __builtin_amdgcn_rcpf(1.0f + e) - 1.0f;
        }

        // ---- gate dots: 8 rows x 24 cols, broadcast LDS reads (bank-perfect) ----
        float p0 = 0.f, p1 = 0.f, p2 = 0.f, p3 = 0.f,
              p4 = 0.f, p5 = 0.f, p6 = 0.f, p7 = 0.f;
        const uint4* A = (const uint4*)hx[par];
        #pragma unroll
        for (int q = 0; q < 3; ++q) {
            uint4 av = A[cb * 3 + q];
            h2 a0 = as_h2(av.x), a1 = as_h2(av.y), a2 = as_h2(av.z), a3 = as_h2(av.w);
#define GDOT(c_, pc) pc = dot2(w[c_][q*4+0], a0, pc); pc = dot2(w[c_][q*4+1], a1, pc); \
                     pc = dot2(w[c_][q*4+2], a2, pc); pc = dot2(w[c_][q*4+3], a3, pc);
            GDOT(0, p0) GDOT(1, p1) GDOT(2, p2) GDOT(3, p3)
            GDOT(4, p4) GDOT(5, p5) GDOT(6, p6) GDOT(7, p7)
#undef GDOT
        }

        // ---- y_{t-1} dots (reads h-part of hx[par]) ----
        float py = 0.f;
        #pragma unroll
        for (int q = 0; q < 2; ++q) {
            uint4 hv = A[cb * 2 + q];
            py = dot2(vwreg[q*4+0], as_h2(hv.x), py);
            py = dot2(vwreg[q*4+1], as_h2(hv.y), py);
            py = dot2(vwreg[q*4+2], as_h2(hv.z), py);
            py = dot2(vwreg[q*4+3], as_h2(hv.w), py);
        }

        // ---- butterfly reduce over the 8-lane group: lane cb ends owning row cb ----
        const bool b0 = (cb & 1), b1 = (cb >> 1) & 1, b2 = (cb >> 2) & 1;
        float s0, s1, s2, s3, u0, u1, z;
        { float ka, sa;
          ka = b0 ? p1 : p0; sa = b0 ? p0 : p1; s0 = ka + __shfl_xor(sa, 1);
          ka = b0 ? p3 : p2; sa = b0 ? p2 : p3; s1 = ka + __shfl_xor(sa, 1);
          ka = b0 ? p5 : p4; sa = b0 ? p4 : p5; s2 = ka + __shfl_xor(sa, 1);
          ka = b0 ? p7 : p6; sa = b0 ? p6 : p7; s3 = ka + __shfl_xor(sa, 1);
          ka = b1 ? s1 : s0; sa = b1 ? s0 : s1; u0 = ka + __shfl_xor(sa, 2);
          ka = b1 ? s3 : s2; sa = b1 ? s2 : s3; u1 = ka + __shfl_xor(sa, 2);
          ka = b2 ? u1 : u0; sa = b2 ? u0 : u1; z  = ka + __shfl_xor(sa, 4);
        }

        // ---- activation (branchless: tanh = 2*sigmoid(2z)-1) ----
        const bool isg = (lane_g == 2);
        float sc = isg ? 2.0f : 1.0f;
        float e  = __expf(-sc * z);
        float sg = __builtin_amdgcn_rcpf(1.0f + e);
        float a  = isg ? 2.0f * sg - 1.0f : sg;

        // gather i,f,g,o into the k-owner lane (4k..4k+3 adjacent, DPP-friendly)
        float af = __shfl_xor(a, 1);
        float ag = __shfl_xor(a, 2);
        float ao = __shfl_xor(af, 2);   // lane 4k+2's af == lane 4k+3's a == o

        float hn = ao * tc;             // h_t = o * tanh(c_prev)  (reference quirk)
        c = af * c + a * ag;            // c_t = f*c_prev + i*g  (valid on lane_g==0)

        if (lane_g == 0)
            ((_Float16*)hx[par ^ 1])[kown] = (_Float16)hn;
        if (t + 1 < T_STEPS && tid < 64)
            ((_Float16*)hx[par ^ 1])[128 + tid] = (_Float16)xv;

        // ---- y reduce + store (fire-and-forget global write) ----
        py += __shfl_xor(py, 1);
        py += __shfl_xor(py, 2);
        py += __shfl_xor(py, 4);
        if (t > 0 && is_y && cb == 0)
            out[obase + (size_t)(t - 1) * M_DIM + ym] = py + vbv;

        block_sync_lds();
    }

    // ---- final y for t = T-1 (h_{T-1} in hx[0]: last write went to par^1 = 0) ----
    {
        const uint4* H = (const uint4*)hx[0];
        float py = 0.f;
        #pragma unroll
        for (int q = 0; q < 2; ++q) {
            uint4 hv = H[cb * 2 + q];
            py = dot2(vwreg[q*4+0], as_h2(hv.x), py);
            py = dot2(vwreg[q*4+1], as_h2(hv.y), py);
            py = dot2(vwreg[q*4+2], as_h2(hv.z), py);
            py = dot2(vwreg[q*4+3], as_h2(hv.w), py);
        }
        py += __shfl_xor(py, 1);
        py += __shfl_xor(py, 2);
        py += __shfl_xor(py, 4);
        if (is_y && cb == 0)
            out[obase + (size_t)(T_STEPS - 1) * M_DIM + ym] = py + vbv;
    }
}

extern "C" void kernel_launch(void* const* d_in, const int* in_sizes, int n_in,
                              void* d_out, int out_size, void* d_ws, size_t ws_size,
                              hipStream_t stream) {
    const float* x  = (const float*)d_in[0];
    const float* Wi = (const float*)d_in[1];
    const float* Ui = (const float*)d_in[2];
    const float* Wf = (const float*)d_in[3];
    const float* Uf = (const float*)d_in[4];
    const float* Wg = (const float*)d_in[5];
    const float* Ug = (const float*)d_in[6];
    const float* Wo = (const float*)d_in[7];
    const float* Uo = (const float*)d_in[8];
    const float* Vw = (const float*)d_in[9];
    const float* Vb = (const float*)d_in[10];
    float* out = (float*)d_out;

    lstm_fused<<<dim3(B_SZ), dim3(NTH), 0, stream>>>(
        x, Wi, Ui, Wf, Uf, Wg, Ug, Wo, Uo, Vw, Vb, out);
}

// Round 9
// 749.612 us; speedup vs baseline: 1.2672x; 1.2672x over previous
//
#include <hip/hip_runtime.h>
#include <math.h>

typedef _Float16 h2 __attribute__((ext_vector_type(2)));
typedef unsigned int u32;

#define T_STEPS 1024
#define B_SZ    256
#define K_DIM   128
#define IN_DIM  64
#define M_DIM   63
#define NTH     512

__device__ __forceinline__ h2 as_h2(u32 v) { union { u32 u; h2 h; } c; c.u = v; return c.h; }

#if __has_builtin(__builtin_amdgcn_fdot2)
__device__ __forceinline__ float dot2(h2 a, h2 b, float acc) {
    return __builtin_amdgcn_fdot2(a, b, acc, false);
}
#else
__device__ __forceinline__ float dot2(h2 a, h2 b, float acc) {
    return acc + (float)a.x * (float)b.x + (float)a.y * (float)b.y;
}
#endif

// Pure-VALU cross-lane (quad_perm DPP): xor1 = [1,0,3,2] = 0xB1, xor2 = [2,3,0,1] = 0x4E
__device__ __forceinline__ float dpp_xor1(float v) {
    return __int_as_float(__builtin_amdgcn_mov_dpp(__float_as_int(v), 0xB1, 0xF, 0xF, true));
}
__device__ __forceinline__ float dpp_xor2(float v) {
    return __int_as_float(__builtin_amdgcn_mov_dpp(__float_as_int(v), 0x4E, 0xF, 0xF, true));
}
// xor4 within 8-lane group (y reduce): ds_swizzle, LDS pipe, 1 per thread per step
__device__ __forceinline__ float swz_xor4(float v) {
    return __int_as_float(__builtin_amdgcn_ds_swizzle(__float_as_int(v), 0x101F));
}

// LDS-only barrier: do NOT drain vmcnt (x prefetch / y stores stay in flight).
__device__ __forceinline__ void block_sync_lds() {
    asm volatile("s_waitcnt lgkmcnt(0)\n\ts_barrier" ::: "memory");
}

__global__ __launch_bounds__(NTH)
void lstm_fused(const float* __restrict__ x,   // [B,T,IN]
                const float* __restrict__ Wi, const float* __restrict__ Ui,
                const float* __restrict__ Wf, const float* __restrict__ Uf,
                const float* __restrict__ Wg, const float* __restrict__ Ug,
                const float* __restrict__ Wo, const float* __restrict__ Uo,
                const float* __restrict__ Vw, const float* __restrict__ Vb,
                float* __restrict__ out)       // [B,T,M]
{
    // hx: packed-f16 activations, double-buffered. f16[0..127] = h, f16[128..191] = x_t
    __shared__ __align__(16) _Float16 hx[2][192];

    const int b   = blockIdx.x;
    const int tid = threadIdx.x;
    const int rg  = tid >> 2;       // hidden unit owned by this quad (0..127)
    const int cb  = tid & 3;        // col-block / quad lane

    // ---- weights: thread (rg,cb) holds the 4 GATE rows of unit rg,
    //      h2-cols cb*24 .. cb*24+23 of the 96-h2 concat [Uh(64) | Wx(32)]
    h2 w[4][24];   // 96 VGPRs
    #pragma unroll
    for (int g = 0; g < 4; ++g) {
        const float* U = (g == 0) ? Ui : (g == 1) ? Uf : (g == 2) ? Ug : Uo;
        const float* W = (g == 0) ? Wi : (g == 1) ? Wf : (g == 2) ? Wg : Wo;
        const float* urow = U + rg * K_DIM;
        const float* wrow = W + rg * IN_DIM;
        #pragma unroll
        for (int i = 0; i < 24; ++i) {
            int j = cb * 24 + i;                // h2 col in concat layout
            const float* s = (j < 64) ? (urow + 2 * j) : (wrow + 2 * (j - 64));
            float2 v = *(const float2*)s;
            w[g][i] = h2{(_Float16)v.x, (_Float16)v.y};
        }
    }

    // ---- y-projection: 8 threads per output row m; Vw chunk in registers ----
    const int  ym   = tid >> 3;                 // 0..63 (63 used)
    const int  yj   = tid & 7;
    const bool is_y = (tid < 504);
    h2 vwreg[8] = {};
    float vbv = 0.0f;
    if (is_y) {
        const float* src = Vw + ym * K_DIM + yj * 16;
        #pragma unroll
        for (int i = 0; i < 8; ++i)
            vwreg[i] = h2{(_Float16)src[2 * i], (_Float16)src[2 * i + 1]};
        if (yj == 0) vbv = Vb[ym];
    }

    const size_t xbase = (size_t)b * T_STEPS * IN_DIM;
    const size_t obase = (size_t)b * T_STEPS * M_DIM;

    // ---- init: h_{-1}=0, x_0 staged ----
    if (tid < 128) hx[0][tid] = (_Float16)0.f;
    if (tid >= 128 && tid < 192) hx[0][tid] = (_Float16)x[xbase + (tid - 128)];
    float c = 0.0f;   // c[rg], meaningful on cb==0
    __syncthreads();

    for (int t = 0; t < T_STEPS; ++t) {
        const int par = t & 1;

        // x_{t+1} prefetch (cb==1 lanes, rg<64; stays in flight across LDS barrier)
        float xv = 0.0f;
        if (t + 1 < T_STEPS && cb == 1 && rg < IN_DIM)
            xv = x[xbase + (size_t)(t + 1) * IN_DIM + rg];

        // tanh(c_prev) — off the critical path, valid on cb==0
        float tc;
        {
            float e = __expf(-2.0f * c);
            tc = 2.0f * __builtin_amdgcn_rcpf(1.0f + e) - 1.0f;
        }

        // ---- gate dots: 4 gate-rows x 48 cols (6 broadcast b128 reads, bank-disjoint) ----
        float p0 = 0.f, p1 = 0.f, p2 = 0.f, p3 = 0.f;
        const uint4* A = (const uint4*)hx[par];
        #pragma unroll
        for (int q = 0; q < 6; ++q) {
            uint4 av = A[cb * 6 + q];
            h2 a0 = as_h2(av.x), a1 = as_h2(av.y), a2 = as_h2(av.z), a3 = as_h2(av.w);
            p0 = dot2(w[0][q*4+0], a0, p0); p0 = dot2(w[0][q*4+1], a1, p0);
            p0 = dot2(w[0][q*4+2], a2, p0); p0 = dot2(w[0][q*4+3], a3, p0);
            p1 = dot2(w[1][q*4+0], a0, p1); p1 = dot2(w[1][q*4+1], a1, p1);
            p1 = dot2(w[1][q*4+2], a2, p1); p1 = dot2(w[1][q*4+3], a3, p1);
            p2 = dot2(w[2][q*4+0], a0, p2); p2 = dot2(w[2][q*4+1], a1, p2);
            p2 = dot2(w[2][q*4+2], a2, p2); p2 = dot2(w[2][q*4+3], a3, p2);
            p3 = dot2(w[3][q*4+0], a0, p3); p3 = dot2(w[3][q*4+1], a1, p3);
            p3 = dot2(w[3][q*4+2], a2, p3); p3 = dot2(w[3][q*4+3], a3, p3);
        }

        // ---- y_{t-1} dots (reads h-part of hx[par]) ----
        float py = 0.f;
        #pragma unroll
        for (int q = 0; q < 2; ++q) {
            uint4 hv = A[yj * 2 + q];
            py = dot2(vwreg[q*4+0], as_h2(hv.x), py);
            py = dot2(vwreg[q*4+1], as_h2(hv.y), py);
            py = dot2(vwreg[q*4+2], as_h2(hv.z), py);
            py = dot2(vwreg[q*4+3], as_h2(hv.w), py);
        }

        // ---- quad butterfly (DPP only): lane cb ends with z = full row of gate cb ----
        const bool b0 = (cb & 1), b1 = (cb & 2);
        float k0 = b0 ? p1 : p0, s0 = b0 ? p0 : p1;
        float t0 = k0 + dpp_xor1(s0);
        float k1 = b0 ? p3 : p2, s1 = b0 ? p2 : p3;
        float t1 = k1 + dpp_xor1(s1);
        float k2 = b1 ? t1 : t0, s2 = b1 ? t0 : t1;
        float z  = k2 + dpp_xor2(s2);

        // ---- activation (gate cb): branchless sigma / tanh = 2*sigma(2z)-1 ----
        const bool isg = (cb == 2);
        float sc = isg ? 2.0f : 1.0f;
        float e  = __expf(-sc * z);
        float sg = __builtin_amdgcn_rcpf(1.0f + e);
        float a  = isg ? 2.0f * sg - 1.0f : sg;

        // ---- allgather i,f,g,o within the quad (3 DPP movs) ----
        float a1g = dpp_xor1(a);    // gate cb^1
        float a2g = dpp_xor2(a);    // gate cb^2
        float a3g = dpp_xor2(a1g);  // gate cb^3

        // ---- state update on cb==0: a=i, a1g=f, a2g=g, a3g=o ----
        if (cb == 0) {
            float hn = a3g * tc;            // h_t = o * tanh(c_prev)  (reference quirk)
            c = a1g * c + a * a2g;          // c_t = f*c_prev + i*g
            hx[par ^ 1][rg] = (_Float16)hn;
        }
        if (t + 1 < T_STEPS && cb == 1 && rg < IN_DIM)
            hx[par ^ 1][128 + rg] = (_Float16)xv;

        // ---- y reduce (2 DPP + 1 swizzle) + fire-and-forget store ----
        py += dpp_xor1(py);
        py += dpp_xor2(py);
        py += swz_xor4(py);
        if (t > 0 && is_y && yj == 0)
            out[obase + (size_t)(t - 1) * M_DIM + ym] = py + vbv;

        block_sync_lds();
    }

    // ---- final y for t = T-1 (h_{T-1} in hx[0]: T even) ----
    {
        const uint4* A0 = (const uint4*)hx[0];
        float py = 0.f;
        #pragma unroll
        for (int q = 0; q < 2; ++q) {
            uint4 hv = A0[yj * 2 + q];
            py = dot2(vwreg[q*4+0], as_h2(hv.x), py);
            py = dot2(vwreg[q*4+1], as_h2(hv.y), py);
            py = dot2(vwreg[q*4+2], as_h2(hv.z), py);
            py = dot2(vwreg[q*4+3], as_h2(hv.w), py);
        }
        py += dpp_xor1(py);
        py += dpp_xor2(py);
        py += swz_xor4(py);
        if (is_y && yj == 0)
            out[obase + (size_t)(T_STEPS - 1) * M_DIM + ym] = py + vbv;
    }
}

extern "C" void kernel_launch(void* const* d_in, const int* in_sizes, int n_in,
                              void* d_out, int out_size, void* d_ws, size_t ws_size,
                              hipStream_t stream) {
    const float* x  = (const float*)d_in[0];
    const float* Wi = (const float*)d_in[1];
    const float* Ui = (const float*)d_in[2];
    const float* Wf = (const float*)d_in[3];
    const float* Uf = (const float*)d_in[4];
    const float* Wg = (const float*)d_in[5];
    const float* Ug = (const float*)d_in[6];
    const float* Wo = (const float*)d_in[7];
    const float* Uo = (const float*)d_in[8];
    const float* Vw = (const float*)d_in[9];
    const float* Vb = (const float*)d_in[10];
    float* out = (float*)d_out;

    lstm_fused<<<dim3(B_SZ), dim3(NTH), 0, stream>>>(
        x, Wi, Ui, Wf, Uf, Wg, Ug, Wo, Uo, Vw, Vb, out);
}